// Round 11
// baseline (798.101 us; speedup 1.0000x reference)
//
#include <hip/hip_runtime.h>
#include <hip/hip_bf16.h>

// RecallModel: B=16, L=2048, H=64, NH=2, HD=32, M=8, V=64.
// Inputs: ints int32; floats FP32. OUTPUTS FLOAT32 (reference dtype!):
//   out_f[0] = loss, out_f[1..1+16*2048*2048) = attn_w (B,L,L). 268,435,460 B.
//
// d_ws usage:
//   qk15 @0       524,288 B  bf16 [Qs|K] batch 15 (layer 2)
//   imp  @524288  131,072 B  f32 imp[16][2048] (ONLY row 15 used: zeroed by
//                                 k_qkv<0> block 0, filled by fused imp15)
//   l2   @655360  262,144 B  f32 sum-of-exp
// d_out doubles as scratch (dead-before-overwrite). attn batch-b region =
// bytes [4 + b*16777216, 4 + (b+1)*16777216).
//   qk1    @ byte 4194368    8 MB bf16 layer-1 [Qs|K] rows s128 (dies at attn1)
//   vg1    @ byte 12582976   4 MB bf16 layer-1 V, j-tiled (dies at attn1)
//   vg2    @ byte 4194368    4 MB bf16 layer-2 V, j-tiled (dies at attn2)
//   qk0-14 @ byte 251658304  7.5 MB (region-15 head; dies at pass2 wave2)
//   h      @ byte 259522624  4 MB bf16 (region-15 tail; survives pass2 wave1;
//                                 dies at pass2 wave2)
//   Ppart  @ byte 263716928  4 MB f32 [32 qt][16 bz][2048] importance partials
//                                 (bz rows 0-14 written by pass2 wave1; dies
//                                 at pass2 wave2)
// ORDER (9 launches): qkv1(embed-fused) -> attn1 -> ffn1 -> qkv2 -> attn2 ->
// ffn2 -> pass2 wave1 (bz0-14 + fused bz15 importance, grid 4096) ->
// k_select (reduce+topk+loss -> out_f[0]) -> pass2 wave2 (bz15).
//
// V j-tiled layout (per batch): element (j,d) at
//   ((( (j>>5)*4 + ((j>>2)&3) )*64 + d)*8 + ((j>>4)&1)*4 + (j&3)

typedef unsigned short u16;
#define LQ 2048
#define BBATCH 16
#define QKB 262144   // u16 elements per batch of packed [Qs|K] (2048*128)

typedef __attribute__((ext_vector_type(8))) short bf16x8;
typedef __attribute__((ext_vector_type(4))) float f32x4;

__device__ __forceinline__ float bfu2f(u16 x){ return __uint_as_float(((unsigned)x) << 16); }
__device__ __forceinline__ u16 f2bu(float f){ return __bfloat16_as_ushort(__float2bfloat16(f)); }

// packed f32x2 -> bf16x2 (RNE, same rounding as f2bu), lo in [15:0]
__device__ __forceinline__ unsigned cvtpk(float lo, float hi){
  unsigned r;
  asm("v_cvt_pk_bf16_f32 %0, %1, %2" : "=v"(r) : "v"(lo), "v"(hi));
  return r;
}

__device__ __forceinline__ const u16* qk_rowp(const u16* qk_r15, const u16* qk_ws,
                                              int bz, int row){
  const u16* base = (bz < 15) ? (qk_r15 + (size_t)bz*QKB) : qk_ws;
  return base + (size_t)row*128;
}
__device__ __forceinline__ u16* qk_rowp_w(u16* qk_r15, u16* qk_ws, int bz, int row){
  u16* base = (bz < 15) ? (qk_r15 + (size_t)bz*QKB) : qk_ws;
  return base + (size_t)row*128;
}

// ---------------- qkv projection (MFMA), embed-fused for layer 1 ------------
// MODE 0: gathers X = bf16(emb[seq]) directly (RNE cvtpk == f2bu -> h bits
// identical to the old k_embed), writes h for the residual path, and block 0
// zeroes ws_imp row 15 + out_f[0]. MODE 1: reads X = h.
// out^T = mfma(W_frag, X_frag): lane (gq,n) holds out[tok n][ct*16+gq*4+r]
// (m<64: Q*qs, <128: K, else V). Staged via LDS YL32[64 tok][97 u32], then
// vectorized writes: [Qs|K] rows as u32, V as 8-B packed j-groups (j-tiled).
template<int MODE>
__global__ __launch_bounds__(256) void k_qkv(const u16* __restrict__ X,
                                             const int* __restrict__ seq,
                                             const float* __restrict__ emb,
                                             const float* __restrict__ W,
                                             const float* __restrict__ bias,
                                             u16* __restrict__ dqk0,
                                             u16* __restrict__ dqk_r15,
                                             u16* __restrict__ dqk_ws,
                                             u16* __restrict__ vg,
                                             u16* __restrict__ hw,
                                             float* __restrict__ imp15,
                                             float* __restrict__ out0){
  __shared__ u16 WL[192*64];         // [m][k] bf16, k XOR-swizzled by (m&7)
  __shared__ unsigned YL32[64*97];   // [tok][u32 col] packed outputs
  __shared__ float BS[192];
  const int t = threadIdx.x;
  if (MODE==0 && blockIdx.x==0){
    #pragma unroll
    for (int i=0;i<8;i++) imp15[i*256 + t] = 0.f;
    if (t==0) out0[0] = 0.f;
  }
  for (int e=t; e<12288; e+=256){
    int m = e>>6, k = e&63;
    WL[m*64 + (k ^ ((m&7)<<3))] = f2bu(W[e]);
  }
  if (t < 192) BS[t] = bias[t];
  __syncthreads();
  const int lane = t & 63, wv = t >> 6;
  const int n = lane & 15, gq = lane >> 4;
  const int tok0 = blockIdx.x*64;
  const int tl = wv*16 + n;          // local token of this lane's B-column
  bf16x8 xf0, xf1;
  if (MODE==0){
    int vv = seq[tok0+tl] & 63;
    const float* er = emb + (vv << 6);
    float4 p0 = *(const float4*)(er + gq*8);
    float4 p1 = *(const float4*)(er + gq*8 + 4);
    float4 p2 = *(const float4*)(er + 32 + gq*8);
    float4 p3 = *(const float4*)(er + 32 + gq*8 + 4);
    union { unsigned u[4]; bf16x8 v; } u0, u1;
    u0.u[0]=cvtpk(p0.x,p0.y); u0.u[1]=cvtpk(p0.z,p0.w);
    u0.u[2]=cvtpk(p1.x,p1.y); u0.u[3]=cvtpk(p1.z,p1.w);
    u1.u[0]=cvtpk(p2.x,p2.y); u1.u[1]=cvtpk(p2.z,p2.w);
    u1.u[2]=cvtpk(p3.x,p3.y); u1.u[3]=cvtpk(p3.z,p3.w);
    xf0 = u0.v; xf1 = u1.v;
    *(bf16x8*)(hw + (size_t)(tok0+tl)*64 + gq*8)      = xf0;
    *(bf16x8*)(hw + (size_t)(tok0+tl)*64 + 32 + gq*8) = xf1;
  } else {
    xf0 = *(const bf16x8*)(X + (size_t)(tok0+tl)*64 + gq*8);
    xf1 = *(const bf16x8*)(X + (size_t)(tok0+tl)*64 + 32 + gq*8);
  }
  const float qs = 0.17677669529663688f;  // 1/sqrt(32)
  #pragma unroll
  for (int ct=0; ct<12; ct++){
    f32x4 c;
    #pragma unroll
    for (int r=0;r<4;r++) c[r] = BS[ct*16 + gq*4 + r];
    bf16x8 wf0 = *(const bf16x8*)(WL + (ct*16+n)*64 + ((gq*8) ^ ((n&7)<<3)));
    bf16x8 wf1 = *(const bf16x8*)(WL + (ct*16+n)*64 + ((32+gq*8) ^ ((n&7)<<3)));
    c = __builtin_amdgcn_mfma_f32_16x16x32_bf16(wf0, xf0, c, 0, 0, 0);
    c = __builtin_amdgcn_mfma_f32_16x16x32_bf16(wf1, xf1, c, 0, 0, 0);
    if (ct < 4){ c[0]*=qs; c[1]*=qs; c[2]*=qs; c[3]*=qs; }
    YL32[tl*97 + ct*8 + gq*2]     = cvtpk(c[0], c[1]);
    YL32[tl*97 + ct*8 + gq*2 + 1] = cvtpk(c[2], c[3]);
  }
  __syncthreads();
  const int b = tok0 >> 11, rbase = tok0 & 2047;
  // [Qs|K] rows: u32 cols 0..63 (m 0..127)
  #pragma unroll
  for (int i=0;i<16;i++){
    int idx = i*256 + t;
    int rl = idx>>6, cc = idx&63;
    u16* row = (MODE==0) ? (dqk0 + (size_t)(tok0+rl)*128)
                         : qk_rowp_w(dqk_r15, dqk_ws, b, rbase+rl);
    ((unsigned*)row)[cc] = YL32[rl*97 + cc];
  }
  // V (u32 cols 64..95 = d pairs): 8-B store covers j-group of 4 tokens
  #pragma unroll
  for (int i=0;i<4;i++){
    int gid = i*256 + t;
    int grp = gid>>6, d = gid&63;
    int j0 = rbase + grp*4;
    unsigned lohi[2];
    #pragma unroll
    for (int p=0;p<2;p++){
      unsigned w0 = YL32[(grp*4 + 2*p)*97 + 64 + (d>>1)];
      unsigned w1 = YL32[(grp*4 + 2*p + 1)*97 + 64 + (d>>1)];
      u16 a  = (d&1) ? (u16)(w0>>16) : (u16)(w0 & 0xffffu);
      u16 bb = (d&1) ? (u16)(w1>>16) : (u16)(w1 & 0xffffu);
      lohi[p] = (unsigned)a | ((unsigned)bb << 16);
    }
    size_t A = ((size_t)((b*64 + (j0>>5))*4 + ((j0>>2)&3))*64 + d)*8 + ((j0>>4)&1)*4;
    *(uint2*)(vg + A) = make_uint2(lohi[0], lohi[1]);
  }
}

// ---------------- attention v3 (MFMA) + fused proj+residual+LN --------------
// Block = 64 queries (4 q-sets of 16); 4 waves SPLIT THE KEY RANGE (512 keys
// each). K/V fragments loaded ONCE per k-tile, amortized over FOUR q-sets
// (halves HBM K/V traffic vs v2: 64 q/block -> 32 blocks/batch * 768 KB =
// 24 MB/batch, 384 MB total). Grid 512 = 2 blocks/CU, single dispatch round
// -> XCD swizzle deterministic (XCD x gets batches {2x,2x+1}).
// exp in f32; P packed via v_cvt_pk_bf16_f32; PV A-frag built in-lane.
// No barriers in the main loop. Partial O / denominators combined via LDS
// atomicAdd, then proj+residual+LN. Summation order per (q,k) identical to
// v2 (key-split unchanged) -> bit-stable.
template<int MODE>
__global__ __launch_bounds__(256) void k_attn_ln(const u16* __restrict__ PQK,
    const u16* __restrict__ QKWS, const u16* __restrict__ VG,
    const float* __restrict__ wo, const float* __restrict__ bo,
    const float* __restrict__ g, const float* __restrict__ be,
    u16* __restrict__ h, float* __restrict__ lout){
  __shared__ float R[4096];          // phase A: OACC[64][64]; phase B: WOT
  __shared__ float ST[64*68];        // [q][d] normalized attn out (padded)
  __shared__ float DN[2][64];        // denominator accumulators
  __shared__ float CB[192];          // bo | g | be
  const int lin = blockIdx.x;        // 512 blocks = 8 XCD * 64
  const int nid = (lin & 7)*64 + (lin >> 3);
  const int qt = nid & 31, bz = nid >> 5;
  const int t = threadIdx.x;
  const int lane = t & 63, wv = t >> 6;
  const int n = lane & 15, gq = lane >> 4;
  const f32x4 FZ = {0.f, 0.f, 0.f, 0.f};

  for (int e=t; e<4096; e+=256) R[e] = 0.f;
  if (t < 128) DN[t>>6][t&63] = 0.f;
  __syncthreads();

  bf16x8 qf[4][2];
  #pragma unroll
  for (int qa=0; qa<4; qa++){
    const u16* qrow = (MODE==0) ? (PQK + (size_t)(bz*LQ + qt*64 + qa*16 + n)*128)
                                : qk_rowp(PQK, QKWS, bz, qt*64 + qa*16 + n);
    qf[qa][0] = *(const bf16x8*)(qrow + gq*8);
    qf[qa][1] = *(const bf16x8*)(qrow + 32 + gq*8);
  }
  f32x4 o[4][2][2];                  // [qa][hh][db]
  #pragma unroll
  for (int qa=0; qa<4; qa++)
    #pragma unroll
    for (int hh=0; hh<2; hh++)
      #pragma unroll
      for (int db=0; db<2; db++) o[qa][hh][db] = FZ;
  float dacc[4][2];
  #pragma unroll
  for (int qa=0; qa<4; qa++){ dacc[qa][0]=0.f; dacc[qa][1]=0.f; }

  #pragma unroll 1
  for (int kt=wv*8; kt<wv*8+8; kt++){
    #pragma unroll
    for (int hh=0; hh<2; hh++){
      bf16x8 kf[4];
      #pragma unroll
      for (int jb=0; jb<4; jb++){
        const u16* kr = (MODE==0) ? (PQK + (size_t)(bz*LQ + kt*64 + jb*16 + n)*128)
                                  : qk_rowp(PQK, QKWS, bz, kt*64 + jb*16 + n);
        kf[jb] = *(const bf16x8*)(kr + 64 + hh*32 + gq*8);
      }
      unsigned pk[4][4][2];
      #pragma unroll
      for (int qa=0; qa<4; qa++){
        f32x4 ev[4];
        #pragma unroll
        for (int jb=0; jb<4; jb++)
          ev[jb] = __builtin_amdgcn_mfma_f32_16x16x32_bf16(kf[jb], qf[qa][hh], FZ, 0, 0, 0);
        float ds = 0.f;
        #pragma unroll
        for (int jb=0; jb<4; jb++){
          float e0 = __expf(ev[jb][0]), e1 = __expf(ev[jb][1]);
          float e2 = __expf(ev[jb][2]), e3 = __expf(ev[jb][3]);
          ds += (e0+e1) + (e2+e3);
          pk[qa][jb][0] = cvtpk(e0, e1);
          pk[qa][jb][1] = cvtpk(e2, e3);
        }
        dacc[qa][hh] += ds;
      }
      #pragma unroll
      for (int kb=0; kb<2; kb++){
        union { unsigned u[4]; bf16x8 v; } af[4];
        #pragma unroll
        for (int qa=0; qa<4; qa++){
          af[qa].u[0] = pk[qa][2*kb][0];   af[qa].u[1] = pk[qa][2*kb][1];
          af[qa].u[2] = pk[qa][2*kb+1][0]; af[qa].u[3] = pk[qa][2*kb+1][1];
        }
        #pragma unroll
        for (int db=0; db<2; db++){
          const int d = hh*32 + db*16 + n;
          const bf16x8 vf = *(const bf16x8*)(VG +
              ((size_t)((bz*64 + kt*2 + kb)*4 + gq)*64 + d)*8);
          #pragma unroll
          for (int qa=0; qa<4; qa++)
            o[qa][hh][db] = __builtin_amdgcn_mfma_f32_16x16x32_bf16(af[qa].v, vf, o[qa][hh][db], 0, 0, 0);
        }
      }
    }
  }
  #pragma unroll
  for (int qa=0; qa<4; qa++)
    #pragma unroll
    for (int hh=0; hh<2; hh++){
      float s = dacc[qa][hh];
      s += __shfl_xor(s, 16);
      s += __shfl_xor(s, 32);
      if (gq == 0) atomicAdd(&DN[hh][qa*16 + n], s);
    }
  #pragma unroll
  for (int qa=0; qa<4; qa++)
    #pragma unroll
    for (int hh=0; hh<2; hh++)
      #pragma unroll
      for (int db=0; db<2; db++)
        #pragma unroll
        for (int r=0; r<4; r++)
          atomicAdd(&R[(qa*16 + gq*4 + r)*64 + hh*32 + db*16 + n], o[qa][hh][db][r]);
  __syncthreads();
  if (lout && t < 128)
    lout[(size_t)(bz*2 + (t>>6))*LQ + qt*64 + (t&63)] = DN[t>>6][t&63];
  for (int e=t; e<4096; e+=256){
    int q = e >> 6, d = e & 63;
    ST[q*68 + d] = R[e] / DN[d>>5][q];
  }
  __syncthreads();                   // OACC dead; reuse R as WOT
  for (int e2=t; e2<4096; e2+=256){ int k=e2>>6, mo=e2&63; R[e2] = wo[mo*64+k]; }
  if (t < 64)       CB[t] = bo[t];
  else if (t < 128) CB[t] = g[t-64];
  else if (t < 192) CB[t] = be[t-128];
  __syncthreads();
  for (int r=0; r<16; r++){
    int tl = wv*16 + r;
    size_t gtok = (size_t)(bz*LQ + qt*64 + tl);
    float acc = CB[lane];
    for (int k=0; k<64; k++) acc += ST[tl*68 + k] * R[k*64 + lane];
    float rr = acc + bfu2f(h[gtok*64 + lane]);
    float s = rr;
    #pragma unroll
    for (int ofs=32; ofs; ofs>>=1) s += __shfl_xor(s, ofs);
    float mean = s * (1.f/64.f);
    float dv = rr - mean;
    float vs = dv*dv;
    #pragma unroll
    for (int ofs=32; ofs; ofs>>=1) vs += __shfl_xor(vs, ofs);
    float rstd = 1.f/sqrtf(vs*(1.f/64.f) + 1e-5f);
    h[gtok*64 + lane] = f2bu(dv*rstd*CB[64+lane] + CB[128+lane]);
  }
}

// ---------------- fused FFN + residual + LN (MFMA) ----------------
__global__ __launch_bounds__(256) void k_ffn(u16* __restrict__ h,
    const float* __restrict__ w1, const float* __restrict__ b1,
    const float* __restrict__ w2, const float* __restrict__ b2,
    const float* __restrict__ g, const float* __restrict__ be){
  __shared__ u16 W1L[128*64];      // [h1row][64 d] swizzled
  __shared__ u16 W2L[64*192];      // [o][6 kblk * 32] swizzled (4 W2 + 2 I)
  __shared__ u16 YL[64*64];        // y bf16 staging (swizzled by row)
  __shared__ float B1[128], B2F[64], G[64], Bb[64];
  const int t = threadIdx.x;
  for (int e=t; e<8192; e+=256){
    int row = e>>6, col = e&63;
    W1L[row*64 + (col ^ ((row&7)<<3))] = f2bu(w1[e]);
  }
  for (int e=t; e<12288; e+=256){
    int o = e/192, rem = e%192, u = rem>>5, gs = rem&31, gq2 = gs>>3, s = gs&7;
    float val;
    if (u < 4) val = w2[o*128 + u*32 + ((s>>2)<<4) + gq2*4 + (s&3)];
    else { int d = ((u-4)<<5) + gq2*8 + s; val = (d==o) ? 1.f : 0.f; }
    W2L[o*192 + ((u*32+gs) ^ ((o&7)<<3))] = f2bu(val);
  }
  if (t < 128) B1[t] = b1[t];
  if (t < 64){ B2F[t] = b2[t]; G[t] = g[t]; Bb[t] = be[t]; }
  __syncthreads();
  const int lane = t & 63, wv = t >> 6;
  const int n = lane & 15, gq = lane >> 4;
  const int tok0 = blockIdx.x*64 + wv*16;
  bf16x8 xf[2];
  xf[0] = *(const bf16x8*)(h + (size_t)(tok0+n)*64 + gq*8);
  xf[1] = *(const bf16x8*)(h + (size_t)(tok0+n)*64 + 32 + gq*8);
  f32x4 acc1[8];
  #pragma unroll
  for (int ct=0; ct<8; ct++){
    f32x4 c;
    #pragma unroll
    for (int r=0;r<4;r++) c[r] = B1[ct*16 + gq*4 + r];
    bf16x8 w1f0 = *(const bf16x8*)(W1L + (ct*16+n)*64 + ((gq*8) ^ ((n&7)<<3)));
    bf16x8 w1f1 = *(const bf16x8*)(W1L + (ct*16+n)*64 + ((32+gq*8) ^ ((n&7)<<3)));
    c = __builtin_amdgcn_mfma_f32_16x16x32_bf16(w1f0, xf[0], c, 0, 0, 0);
    c = __builtin_amdgcn_mfma_f32_16x16x32_bf16(w1f1, xf[1], c, 0, 0, 0);
    acc1[ct] = c;
  }
  f32x4 acc2[4];
  #pragma unroll
  for (int ot=0; ot<4; ot++)
    #pragma unroll
    for (int r=0;r<4;r++) acc2[ot][r] = B2F[ot*16 + gq*4 + r];
  #pragma unroll
  for (int u=0; u<6; u++){
    union { unsigned uu[4]; bf16x8 v; } bfr;
    if (u < 4){
      #pragma unroll
      for (int i=0;i<4;i++){
        int ct = u*2 + (i>>1);
        float a = fmaxf(acc1[ct][(2*i)&3], 0.f);
        float b = fmaxf(acc1[ct][(2*i+1)&3], 0.f);
        bfr.uu[i] = (unsigned)f2bu(a) | ((unsigned)f2bu(b) << 16);
      }
    } else {
      bfr.v = xf[u-4];
    }
    #pragma unroll
    for (int ot=0; ot<4; ot++){
      bf16x8 w2f = *(const bf16x8*)(W2L + (ot*16+n)*192 + ((u*32+gq*8) ^ ((n&7)<<3)));
      acc2[ot] = __builtin_amdgcn_mfma_f32_16x16x32_bf16(w2f, bfr.v, acc2[ot], 0, 0, 0);
    }
  }
  float s1 = 0.f;
  #pragma unroll
  for (int ot=0;ot<4;ot++)
    #pragma unroll
    for (int r=0;r<4;r++) s1 += acc2[ot][r];
  s1 += __shfl_xor(s1, 16); s1 += __shfl_xor(s1, 32);
  float mean = s1 * (1.f/64.f);
  float s2 = 0.f;
  #pragma unroll
  for (int ot=0;ot<4;ot++)
    #pragma unroll
    for (int r=0;r<4;r++){ float dv = acc2[ot][r]-mean; s2 += dv*dv; }
  s2 += __shfl_xor(s2, 16); s2 += __shfl_xor(s2, 32);
  float rstd = 1.f/sqrtf(s2*(1.f/64.f) + 1e-5f);
  #pragma unroll
  for (int ot=0;ot<4;ot++)
    #pragma unroll
    for (int r=0;r<4;r++){
      int o = ot*16 + gq*4 + r;
      float yv = (acc2[ot][r]-mean)*rstd*G[o] + Bb[o];
      YL[(wv*16+n)*64 + (o ^ ((n&7)<<3))] = f2bu(yv);
    }
  __syncthreads();
  unsigned* h32 = (unsigned*)(h + (size_t)(blockIdx.x)*64*64);
  #pragma unroll
  for (int i=0;i<8;i++){
    int idx = i*64 + lane;
    int row = wv*16 + (idx>>5), c32 = idx&31;
    unsigned vv = *(const unsigned*)(YL + row*64 + ((c32*2) ^ ((row&7)<<3)));
    h32[row*32 + c32] = vv;
  }
}

// ---------------- pass2 (MFMA): scores -> attn_w FLOAT32 (+partial imp) -----
// DOIMP=1: grid 4096, nper=512. nid<3840: pass2 for bz=nid>>8, rem=nid&255,
// qt=rem>>3, ks=rem&7, kt in [ks*4,ks*4+4). nid>=3840: fused bz-15 importance
// (idx=nid-3840: qt=idx>>3, ks=idx&7) -> atomics into imp15.
// DOIMP=0: grid 256, nper=32, bz0=15 (attn_w for batch 15).
// Importance partials: LDS PIMP, one non-atomic store to part[qt][bz][2048].
template<int DOIMP>
__global__ __launch_bounds__(256) void k_pass2(const u16* __restrict__ qk_r15,
    const u16* __restrict__ qk_ws, const float* __restrict__ l2,
    float* __restrict__ part, float* __restrict__ wout,
    float* __restrict__ imp15, int bz0, int nper){
  __shared__ float STG[64*68];       // [q][j] staging, per-wave-private rows
  __shared__ float INVL[128];
  __shared__ float PIMP[256];
  const int x = blockIdx.x;
  const int nid = (x & 7)*nper + (x >> 3);
  const int t = threadIdx.x;
  const int lane = t & 63, wv = t >> 6;
  const int n = lane & 15, gq = lane >> 4;
  const f32x4 FZ = {0.f, 0.f, 0.f, 0.f};

  if (DOIMP && nid >= 3840){
    // ---- fused bz-15 importance ----
    const int idx = nid - 3840;
    const int qt = idx >> 3, ks = idx & 7;
    if (t < 128) INVL[t] = 1.f / l2[(size_t)(15*2 + (t>>6))*LQ + qt*64 + (t&63)];
    PIMP[t] = 0.f;
    bf16x8 qf0, qf1;
    {
      const u16* qrow = qk_rowp(qk_r15, qk_ws, 15, qt*64 + wv*16 + n);
      qf0 = *(const bf16x8*)(qrow + gq*8);
      qf1 = *(const bf16x8*)(qrow + 32 + gq*8);
    }
    __syncthreads();
    float iv0[4], iv1[4];
    #pragma unroll
    for (int r=0;r<4;r++){
      iv0[r] = INVL[wv*16 + gq*4 + r];
      iv1[r] = INVL[64 + wv*16 + gq*4 + r];
    }
    for (int kt=ks*4; kt<ks*4+4; kt++){
      #pragma unroll
      for (int jb=0; jb<4; jb++){
        const u16* kr = qk_rowp(qk_r15, qk_ws, 15, kt*64 + jb*16 + n);
        bf16x8 kf0 = *(const bf16x8*)(kr + 64 + gq*8);
        bf16x8 kf1 = *(const bf16x8*)(kr + 96 + gq*8);
        f32x4 e0 = __builtin_amdgcn_mfma_f32_16x16x32_bf16(qf0, kf0, FZ, 0, 0, 0);
        f32x4 e1 = __builtin_amdgcn_mfma_f32_16x16x32_bf16(qf1, kf1, FZ, 0, 0, 0);
        float cs = 0.f;
        #pragma unroll
        for (int r=0;r<4;r++)
          cs += 0.5f*(__expf(e0[r])*iv0[r] + __expf(e1[r])*iv1[r]);
        cs += __shfl_xor(cs, 16);
        cs += __shfl_xor(cs, 32);
        if (gq == 0) atomicAdd(&PIMP[(kt-ks*4)*64 + jb*16 + n], cs);
      }
    }
    __syncthreads();
    atomicAdd(&imp15[ks*256 + t], PIMP[t]);
    return;
  }

  // ---- pass2 body ----
  const int bz = bz0 + (nid >> 8);
  const int rem = nid & 255;
  const int qt = rem >> 3, ks = rem & 7;
  if (t < 128) INVL[t] = 1.f / l2[(size_t)(bz*2 + (t>>6))*LQ + qt*64 + (t&63)];
  if (DOIMP) PIMP[t] = 0.f;
  bf16x8 qf0, qf1;
  {
    const u16* qrow = qk_rowp(qk_r15, qk_ws, bz, qt*64 + wv*16 + n);
    qf0 = *(const bf16x8*)(qrow + gq*8);
    qf1 = *(const bf16x8*)(qrow + 32 + gq*8);
  }
  __syncthreads();
  const float iv0 = INVL[wv*16 + n], iv1 = INVL[64 + wv*16 + n];
  for (int kt = ks*4; kt < ks*4 + 4; kt++){
    #pragma unroll
    for (int jb=0; jb<4; jb++){
      const u16* kr = qk_rowp(qk_r15, qk_ws, bz, kt*64 + jb*16 + n);
      bf16x8 kf0 = *(const bf16x8*)(kr + 64 + gq*8);
      bf16x8 kf1 = *(const bf16x8*)(kr + 96 + gq*8);
      f32x4 e0 = __builtin_amdgcn_mfma_f32_16x16x32_bf16(kf0, qf0, FZ, 0, 0, 0);
      f32x4 e1 = __builtin_amdgcn_mfma_f32_16x16x32_bf16(kf1, qf1, FZ, 0, 0, 0);
      float4 w4;
      w4.x = 0.5f*(__expf(e0[0])*iv0 + __expf(e1[0])*iv1);
      w4.y = 0.5f*(__expf(e0[1])*iv0 + __expf(e1[1])*iv1);
      w4.z = 0.5f*(__expf(e0[2])*iv0 + __expf(e1[2])*iv1);
      w4.w = 0.5f*(__expf(e0[3])*iv0 + __expf(e1[3])*iv1);
      *(float4*)(&STG[(wv*16 + n)*68 + jb*16 + 4*gq]) = w4;
    }
    size_t base = 1 + (size_t)bz*LQ*LQ + (size_t)(qt*64)*LQ + (size_t)kt*64;
    float p = 0.f;
    for (int r=0; r<16; r++){
      int q = wv*16 + r;
      float v = STG[q*68 + lane];
      __builtin_nontemporal_store(v, &wout[base + (size_t)q*LQ + lane]);
      p += v;
    }
    if (DOIMP) atomicAdd(&PIMP[(kt-ks*4)*64 + lane], p);
  }
  if (DOIMP){
    __syncthreads();
    part[((size_t)qt*16 + bz)*LQ + ks*256 + t] = PIMP[t];
  }
}

// ---------------- reduce + top-k + memory reader + loss (per batch) ---------
__global__ __launch_bounds__(256) void k_select(const float* __restrict__ part,
    const float* __restrict__ imp15, const u16* __restrict__ h,
    const int* __restrict__ query, const int* __restrict__ target,
    const float* __restrict__ qemb, const float* __restrict__ rq_w, const float* __restrict__ rq_b,
    const float* __restrict__ ro_w, const float* __restrict__ ro_b, float* __restrict__ out0){
  __shared__ float v[2048];
  const int b = blockIdx.x, t = threadIdx.x;
  if (b < 15){
    for (int c=t; c<2048; c+=256){
      float s = 0.f;
      #pragma unroll 8
      for (int qt=0; qt<32; qt++) s += part[((size_t)qt*16 + b)*LQ + c];
      v[c] = s;
    }
  } else {
    for (int c=t; c<2048; c+=256) v[c] = imp15[c];
  }
  __syncthreads();
  if (t >= 64) return;
  const int lane = t;
  int topi[8];
  for (int m=0; m<8; m++){
    float best = -1e30f; int besti = 1<<30;
    for (int i=lane; i<2048; i+=64)
      if (v[i] > best || (v[i] == best && i < besti)){ best = v[i]; besti = i; }
    #pragma unroll
    for (int off=32; off; off>>=1){
      float ob = __shfl_xor(best, off);
      int   oi = __shfl_xor(besti, off);
      if (ob > best || (ob == best && oi < besti)){ best = ob; besti = oi; }
    }
    int c = (besti < 0) ? 0 : (besti > 2047 ? 2047 : besti);
    topi[m] = c;
    v[c] = -1e30f;   // all 64 lanes write the same value (same-wave ordering)
  }
  float mv[8];
  #pragma unroll
  for (int m=0; m<8; m++){
    int idx = topi[m] & 2047;
    mv[m] = bfu2f(h[(size_t)(b*LQ + idx)*64 + lane]);
  }
  float qh = qemb[((query[b]&63)<<6) + lane];
  float qd = rq_b[lane];
  for (int k=0;k<64;k++) qd += __shfl(qh,k) * rq_w[lane*64 + k];
  float sc[8];
  #pragma unroll
  for (int m=0;m<8;m++){
    float p = qd * mv[m];
    #pragma unroll
    for (int o=32;o;o>>=1) p += __shfl_xor(p,o);
    sc[m] = p * 0.125f;   // 1/sqrt(64)
  }
  float mx = sc[0];
  #pragma unroll
  for (int m=1;m<8;m++) mx = fmaxf(mx, sc[m]);
  float den = 0.f, rd = 0.f;
  #pragma unroll
  for (int m=0;m<8;m++){ float w = __expf(sc[m]-mx); den += w; rd += w*mv[m]; }
  rd /= den;
  float lg = ro_b[lane];
  for (int d=0;d<64;d++) lg += __shfl(rd,d) * ro_w[lane*64 + d];
  float lmx = lg;
  #pragma unroll
  for (int o=32;o;o>>=1) lmx = fmaxf(lmx, __shfl_xor(lmx,o));
  float ex = __expf(lg - lmx), es = ex;
  #pragma unroll
  for (int o=32;o;o>>=1) es += __shfl_xor(es,o);
  float lt = __shfl(lg, target[b]&63);
  if (lane == 0) atomicAdd(out0, -(lt - lmx - logf(es)) * (1.f/16.f));
}

// ---------------- launch ----------------
extern "C" void kernel_launch(void* const* d_in, const int* in_sizes, int n_in,
                              void* d_out, int out_size, void* d_ws, size_t ws_size,
                              hipStream_t stream){
  const int*   seq    = (const int*)  d_in[0];
  const int*   query  = (const int*)  d_in[1];
  const int*   target = (const int*)  d_in[2];
  const float* embed  = (const float*)d_in[3];
  const float* a1_wi  = (const float*)d_in[4];
  const float* a1_bi  = (const float*)d_in[5];
  const float* a1_wo  = (const float*)d_in[6];
  const float* a1_bo  = (const float*)d_in[7];
  const float* ff1_w1 = (const float*)d_in[8];
  const float* ff1_b1 = (const float*)d_in[9];
  const float* ff1_w2 = (const float*)d_in[10];
  const float* ff1_b2 = (const float*)d_in[11];
  const float* ln1a_g = (const float*)d_in[12];
  const float* ln1a_b = (const float*)d_in[13];
  const float* ln1b_g = (const float*)d_in[14];
  const float* ln1b_b = (const float*)d_in[15];
  const float* a2_wi  = (const float*)d_in[16];
  const float* a2_bi  = (const float*)d_in[17];
  const float* a2_wo  = (const float*)d_in[18];
  const float* a2_bo  = (const float*)d_in[19];
  const float* ff2_w1 = (const float*)d_in[20];
  const float* ff2_b1 = (const float*)d_in[21];
  const float* ff2_w2 = (const float*)d_in[22];
  const float* ff2_b2 = (const float*)d_in[23];
  const float* ln2a_g = (const float*)d_in[24];
  const float* ln2a_b = (const float*)d_in[25];
  const float* ln2b_g = (const float*)d_in[26];
  const float* ln2b_b = (const float*)d_in[27];
  const float* rq_w   = (const float*)d_in[28];
  const float* rq_b   = (const float*)d_in[29];
  const float* ro_w   = (const float*)d_in[30];
  const float* ro_b   = (const float*)d_in[31];
  const float* qemb   = (const float*)d_in[32];

  // d_ws
  char* wsb      = (char*)d_ws;
  u16*  qk_ws    = (u16*)(wsb);                // 524,288 B (batch 15 [Qs|K])
  float* ws_imp  = (float*)(wsb + 524288);     // 131,072 B (row 15 only)
  float* ws_l    = (float*)(wsb + 655360);     // 262,144 B
  float* imp15   = ws_imp + 15*LQ;

  // d_out (FLOAT32, 268,435,460 B) + scratch parking
  float* out_f  = (float*)d_out;
  u16* qk1     = (u16*)((char*)d_out + 4194368);     // 8 MB layer-1 [Qs|K]
  u16* vg1     = (u16*)((char*)d_out + 12582976);    // 4 MB layer-1 V (j-tiled)
  u16* vg2     = (u16*)((char*)d_out + 4194368);     // 4 MB layer-2 V (j-tiled)
  u16* qk_r15  = (u16*)((char*)d_out + 251658304);   // 7.5 MB, region-15 head
  u16* h16     = (u16*)((char*)d_out + 259522624);   // 4 MB, region-15 tail
  float* Ppart = (float*)((char*)d_out + 263716928); // 4 MB, region-15 tail

  // layer 1 (embed fused into qkv; block 0 zeroes imp15 + out_f[0])
  k_qkv<0><<<512,256,0,stream>>>(nullptr, seq, embed, a1_wi, a1_bi,
                                 qk1, nullptr, nullptr, vg1, h16, imp15, out_f);
  k_attn_ln<0><<<512,256,0,stream>>>(qk1, nullptr, vg1,
                                     a1_wo, a1_bo, ln1a_g, ln1a_b, h16, nullptr);
  k_ffn<<<512,256,0,stream>>>(h16, ff1_w1, ff1_b1, ff1_w2, ff1_b2, ln1b_g, ln1b_b);
  // layer 2
  k_qkv<1><<<512,256,0,stream>>>(h16, nullptr, nullptr, a2_wi, a2_bi,
                                 nullptr, qk_r15, qk_ws, vg2, nullptr, nullptr, nullptr);
  k_attn_ln<1><<<512,256,0,stream>>>(qk_r15, qk_ws, vg2,
                                     a2_wo, a2_bo, ln2a_g, ln2a_b, h16, ws_l);
  k_ffn<<<512,256,0,stream>>>(h16, ff2_w1, ff2_b1, ff2_w2, ff2_b2, ln2b_g, ln2b_b);
  // attn_w bz0-14 + partial importance + fused bz15 importance (grid 4096;
  // destroys regions 0-14; h16/Ppart safe in region-15 tail)
  k_pass2<1><<<4096,256,0,stream>>>(qk_r15, qk_ws, ws_l, Ppart, out_f, imp15, 0, 512);
  // reduce + topk + loss (h16/Ppart still alive); loss -> out_f[0]
  k_select<<<16,256,0,stream>>>(Ppart, imp15, h16, query, target, qemb,
                                rq_w, rq_b, ro_w, ro_b, out_f);
  // attn_w bz15 (overwrites region 15: qk_r15 + h16 + Ppart now dead)
  k_pass2<0><<<256,256,0,stream>>>(qk_r15, qk_ws, ws_l, nullptr, out_f, nullptr, 15, 32);
}

// Round 12
// 759.760 us; speedup vs baseline: 1.0505x; 1.0505x over previous
//
#include <hip/hip_runtime.h>
#include <hip/hip_bf16.h>

// RecallModel: B=16, L=2048, H=64, NH=2, HD=32, M=8, V=64.
// Inputs: ints int32; floats FP32. OUTPUTS FLOAT32 (reference dtype!):
//   out_f[0] = loss, out_f[1..1+16*2048*2048) = attn_w (B,L,L). 268,435,460 B.
//
// == REVERT to round-10 best (760.9 us): attention v2 (32q/block, grid 1024),
// == 9 launches. Round-11's 64q/block variant regressed (+37 us: VGPR pressure
// == dropped occupancy to 2 waves/SIMD; attention is not HBM-bound).
//
// d_ws usage:
//   qk15 @0       524,288 B  bf16 [Qs|K] batch 15 (layer 2)
//   imp  @524288  131,072 B  f32 imp[16][2048] (ONLY row 15 used: zeroed by
//                                 k_qkv<0> block 0, filled by fused imp15)
//   l2   @655360  262,144 B  f32 sum-of-exp
// d_out doubles as scratch (dead-before-overwrite). attn batch-b region =
// bytes [4 + b*16777216, 4 + (b+1)*16777216).
//   qk1    @ byte 4194368    8 MB bf16 layer-1 [Qs|K] rows s128 (dies at attn1)
//   vg1    @ byte 12582976   4 MB bf16 layer-1 V, j-tiled (dies at attn1)
//   vg2    @ byte 4194368    4 MB bf16 layer-2 V, j-tiled (dies at attn2)
//   qk0-14 @ byte 251658304  7.5 MB (region-15 head; dies at pass2 wave2)
//   h      @ byte 259522624  4 MB bf16 (region-15 tail; survives pass2 wave1;
//                                 dies at pass2 wave2)
//   Ppart  @ byte 263716928  4 MB f32 [32 qt][16 bz][2048] importance partials
//                                 (bz rows 0-14 written by pass2 wave1; dies
//                                 at pass2 wave2)
// ORDER (9 launches): qkv1(embed-fused) -> attn1 -> ffn1 -> qkv2 -> attn2 ->
// ffn2 -> pass2 wave1 (bz0-14 + fused bz15 importance, grid 4096) ->
// k_select (reduce+topk+loss -> out_f[0]) -> pass2 wave2 (bz15).
//
// V j-tiled layout (per batch): element (j,d) at
//   ((( (j>>5)*4 + ((j>>2)&3) )*64 + d)*8 + ((j>>4)&1)*4 + (j&3)

typedef unsigned short u16;
#define LQ 2048
#define BBATCH 16
#define QKB 262144   // u16 elements per batch of packed [Qs|K] (2048*128)

typedef __attribute__((ext_vector_type(8))) short bf16x8;
typedef __attribute__((ext_vector_type(4))) float f32x4;

__device__ __forceinline__ float bfu2f(u16 x){ return __uint_as_float(((unsigned)x) << 16); }
__device__ __forceinline__ u16 f2bu(float f){ return __bfloat16_as_ushort(__float2bfloat16(f)); }

// packed f32x2 -> bf16x2 (RNE, same rounding as f2bu), lo in [15:0]
__device__ __forceinline__ unsigned cvtpk(float lo, float hi){
  unsigned r;
  asm("v_cvt_pk_bf16_f32 %0, %1, %2" : "=v"(r) : "v"(lo), "v"(hi));
  return r;
}

__device__ __forceinline__ const u16* qk_rowp(const u16* qk_r15, const u16* qk_ws,
                                              int bz, int row){
  const u16* base = (bz < 15) ? (qk_r15 + (size_t)bz*QKB) : qk_ws;
  return base + (size_t)row*128;
}
__device__ __forceinline__ u16* qk_rowp_w(u16* qk_r15, u16* qk_ws, int bz, int row){
  u16* base = (bz < 15) ? (qk_r15 + (size_t)bz*QKB) : qk_ws;
  return base + (size_t)row*128;
}

// ---------------- qkv projection (MFMA), embed-fused for layer 1 ------------
// MODE 0: gathers X = bf16(emb[seq]) directly (RNE cvtpk == f2bu -> h bits
// identical to the old k_embed), writes h for the residual path, and block 0
// zeroes ws_imp row 15 + out_f[0]. MODE 1: reads X = h.
// out^T = mfma(W_frag, X_frag): lane (gq,n) holds out[tok n][ct*16+gq*4+r]
// (m<64: Q*qs, <128: K, else V). Staged via LDS YL32[64 tok][97 u32], then
// vectorized writes: [Qs|K] rows as u32, V as 8-B packed j-groups (j-tiled).
template<int MODE>
__global__ __launch_bounds__(256) void k_qkv(const u16* __restrict__ X,
                                             const int* __restrict__ seq,
                                             const float* __restrict__ emb,
                                             const float* __restrict__ W,
                                             const float* __restrict__ bias,
                                             u16* __restrict__ dqk0,
                                             u16* __restrict__ dqk_r15,
                                             u16* __restrict__ dqk_ws,
                                             u16* __restrict__ vg,
                                             u16* __restrict__ hw,
                                             float* __restrict__ imp15,
                                             float* __restrict__ out0){
  __shared__ u16 WL[192*64];         // [m][k] bf16, k XOR-swizzled by (m&7)
  __shared__ unsigned YL32[64*97];   // [tok][u32 col] packed outputs
  __shared__ float BS[192];
  const int t = threadIdx.x;
  if (MODE==0 && blockIdx.x==0){
    #pragma unroll
    for (int i=0;i<8;i++) imp15[i*256 + t] = 0.f;
    if (t==0) out0[0] = 0.f;
  }
  for (int e=t; e<12288; e+=256){
    int m = e>>6, k = e&63;
    WL[m*64 + (k ^ ((m&7)<<3))] = f2bu(W[e]);
  }
  if (t < 192) BS[t] = bias[t];
  __syncthreads();
  const int lane = t & 63, wv = t >> 6;
  const int n = lane & 15, gq = lane >> 4;
  const int tok0 = blockIdx.x*64;
  const int tl = wv*16 + n;          // local token of this lane's B-column
  bf16x8 xf0, xf1;
  if (MODE==0){
    int vv = seq[tok0+tl] & 63;
    const float* er = emb + (vv << 6);
    float4 p0 = *(const float4*)(er + gq*8);
    float4 p1 = *(const float4*)(er + gq*8 + 4);
    float4 p2 = *(const float4*)(er + 32 + gq*8);
    float4 p3 = *(const float4*)(er + 32 + gq*8 + 4);
    union { unsigned u[4]; bf16x8 v; } u0, u1;
    u0.u[0]=cvtpk(p0.x,p0.y); u0.u[1]=cvtpk(p0.z,p0.w);
    u0.u[2]=cvtpk(p1.x,p1.y); u0.u[3]=cvtpk(p1.z,p1.w);
    u1.u[0]=cvtpk(p2.x,p2.y); u1.u[1]=cvtpk(p2.z,p2.w);
    u1.u[2]=cvtpk(p3.x,p3.y); u1.u[3]=cvtpk(p3.z,p3.w);
    xf0 = u0.v; xf1 = u1.v;
    *(bf16x8*)(hw + (size_t)(tok0+tl)*64 + gq*8)      = xf0;
    *(bf16x8*)(hw + (size_t)(tok0+tl)*64 + 32 + gq*8) = xf1;
  } else {
    xf0 = *(const bf16x8*)(X + (size_t)(tok0+tl)*64 + gq*8);
    xf1 = *(const bf16x8*)(X + (size_t)(tok0+tl)*64 + 32 + gq*8);
  }
  const float qs = 0.17677669529663688f;  // 1/sqrt(32)
  #pragma unroll
  for (int ct=0; ct<12; ct++){
    f32x4 c;
    #pragma unroll
    for (int r=0;r<4;r++) c[r] = BS[ct*16 + gq*4 + r];
    bf16x8 wf0 = *(const bf16x8*)(WL + (ct*16+n)*64 + ((gq*8) ^ ((n&7)<<3)));
    bf16x8 wf1 = *(const bf16x8*)(WL + (ct*16+n)*64 + ((32+gq*8) ^ ((n&7)<<3)));
    c = __builtin_amdgcn_mfma_f32_16x16x32_bf16(wf0, xf0, c, 0, 0, 0);
    c = __builtin_amdgcn_mfma_f32_16x16x32_bf16(wf1, xf1, c, 0, 0, 0);
    if (ct < 4){ c[0]*=qs; c[1]*=qs; c[2]*=qs; c[3]*=qs; }
    YL32[tl*97 + ct*8 + gq*2]     = cvtpk(c[0], c[1]);
    YL32[tl*97 + ct*8 + gq*2 + 1] = cvtpk(c[2], c[3]);
  }
  __syncthreads();
  const int b = tok0 >> 11, rbase = tok0 & 2047;
  // [Qs|K] rows: u32 cols 0..63 (m 0..127)
  #pragma unroll
  for (int i=0;i<16;i++){
    int idx = i*256 + t;
    int rl = idx>>6, cc = idx&63;
    u16* row = (MODE==0) ? (dqk0 + (size_t)(tok0+rl)*128)
                         : qk_rowp_w(dqk_r15, dqk_ws, b, rbase+rl);
    ((unsigned*)row)[cc] = YL32[rl*97 + cc];
  }
  // V (u32 cols 64..95 = d pairs): 8-B store covers j-group of 4 tokens
  #pragma unroll
  for (int i=0;i<4;i++){
    int gid = i*256 + t;
    int grp = gid>>6, d = gid&63;
    int j0 = rbase + grp*4;
    unsigned lohi[2];
    #pragma unroll
    for (int p=0;p<2;p++){
      unsigned w0 = YL32[(grp*4 + 2*p)*97 + 64 + (d>>1)];
      unsigned w1 = YL32[(grp*4 + 2*p + 1)*97 + 64 + (d>>1)];
      u16 a  = (d&1) ? (u16)(w0>>16) : (u16)(w0 & 0xffffu);
      u16 bb = (d&1) ? (u16)(w1>>16) : (u16)(w1 & 0xffffu);
      lohi[p] = (unsigned)a | ((unsigned)bb << 16);
    }
    size_t A = ((size_t)((b*64 + (j0>>5))*4 + ((j0>>2)&3))*64 + d)*8 + ((j0>>4)&1)*4;
    *(uint2*)(vg + A) = make_uint2(lohi[0], lohi[1]);
  }
}

// ---------------- attention v2 (MFMA) + fused proj+residual+LN --------------
// Block = 32 queries (2 q-sets of 16); 4 waves SPLIT THE KEY RANGE (512 keys
// each). K/V fragments loaded ONCE per k-tile, reused by both q-sets.
// exp in f32; P packed via v_cvt_pk_bf16_f32; PV A-frag built in-lane.
// No barriers in the main loop. Partial O / denominators combined via LDS
// atomicAdd, then proj+residual+LN.
// Grid 1024, XCD-bijective remap: XCD x gets batches {2x, 2x+1}.
// NOTE: no min-waves in launch_bounds (R8->R9 lesson: clamping VGPR to 128
// hurts; compiler floats to its natural allocation at 3 waves/SIMD).
template<int MODE>
__global__ __launch_bounds__(256) void k_attn_ln(const u16* __restrict__ PQK,
    const u16* __restrict__ QKWS, const u16* __restrict__ VG,
    const float* __restrict__ wo, const float* __restrict__ bo,
    const float* __restrict__ g, const float* __restrict__ be,
    u16* __restrict__ h, float* __restrict__ lout){
  __shared__ float R[4096];          // phase A: OACC[32][64]; phase B: WOT
  __shared__ float ST[32*68];        // [q][d] normalized attn out (padded)
  __shared__ float DN[2][32];        // denominator accumulators
  __shared__ float CB[192];          // bo | g | be
  const int lin = blockIdx.x;        // 1024 blocks = 8 XCD * 128
  const int nid = (lin & 7)*128 + (lin >> 3);
  const int qt = nid & 63, bz = nid >> 6;
  const int t = threadIdx.x;
  const int lane = t & 63, wv = t >> 6;
  const int n = lane & 15, gq = lane >> 4;
  const f32x4 FZ = {0.f, 0.f, 0.f, 0.f};

  for (int e=t; e<2048; e+=256) R[e] = 0.f;
  if (t < 64) DN[t>>5][t&31] = 0.f;
  __syncthreads();

  bf16x8 qf[2][2];
  #pragma unroll
  for (int qa=0; qa<2; qa++){
    const u16* qrow = (MODE==0) ? (PQK + (size_t)(bz*LQ + qt*32 + qa*16 + n)*128)
                                : qk_rowp(PQK, QKWS, bz, qt*32 + qa*16 + n);
    qf[qa][0] = *(const bf16x8*)(qrow + gq*8);
    qf[qa][1] = *(const bf16x8*)(qrow + 32 + gq*8);
  }
  f32x4 o[2][2][2];                  // [qa][hh][db]
  #pragma unroll
  for (int qa=0; qa<2; qa++)
    #pragma unroll
    for (int hh=0; hh<2; hh++)
      #pragma unroll
      for (int db=0; db<2; db++) o[qa][hh][db] = FZ;
  float dacc[2][2] = {{0.f,0.f},{0.f,0.f}};

  #pragma unroll 1
  for (int kt=wv*8; kt<wv*8+8; kt++){
    #pragma unroll
    for (int hh=0; hh<2; hh++){
      bf16x8 kf[4];
      #pragma unroll
      for (int jb=0; jb<4; jb++){
        const u16* kr = (MODE==0) ? (PQK + (size_t)(bz*LQ + kt*64 + jb*16 + n)*128)
                                  : qk_rowp(PQK, QKWS, bz, kt*64 + jb*16 + n);
        kf[jb] = *(const bf16x8*)(kr + 64 + hh*32 + gq*8);
      }
      unsigned pk[2][4][2];
      #pragma unroll
      for (int qa=0; qa<2; qa++){
        f32x4 ev[4];
        #pragma unroll
        for (int jb=0; jb<4; jb++)
          ev[jb] = __builtin_amdgcn_mfma_f32_16x16x32_bf16(kf[jb], qf[qa][hh], FZ, 0, 0, 0);
        float ds = 0.f;
        #pragma unroll
        for (int jb=0; jb<4; jb++){
          float e0 = __expf(ev[jb][0]), e1 = __expf(ev[jb][1]);
          float e2 = __expf(ev[jb][2]), e3 = __expf(ev[jb][3]);
          ds += (e0+e1) + (e2+e3);
          pk[qa][jb][0] = cvtpk(e0, e1);
          pk[qa][jb][1] = cvtpk(e2, e3);
        }
        dacc[qa][hh] += ds;
      }
      #pragma unroll
      for (int kb=0; kb<2; kb++){
        union { unsigned u[4]; bf16x8 v; } af[2];
        #pragma unroll
        for (int qa=0; qa<2; qa++){
          af[qa].u[0] = pk[qa][2*kb][0];   af[qa].u[1] = pk[qa][2*kb][1];
          af[qa].u[2] = pk[qa][2*kb+1][0]; af[qa].u[3] = pk[qa][2*kb+1][1];
        }
        #pragma unroll
        for (int db=0; db<2; db++){
          const int d = hh*32 + db*16 + n;
          const bf16x8 vf = *(const bf16x8*)(VG +
              ((size_t)((bz*64 + kt*2 + kb)*4 + gq)*64 + d)*8);
          #pragma unroll
          for (int qa=0; qa<2; qa++)
            o[qa][hh][db] = __builtin_amdgcn_mfma_f32_16x16x32_bf16(af[qa].v, vf, o[qa][hh][db], 0, 0, 0);
        }
      }
    }
  }
  #pragma unroll
  for (int qa=0; qa<2; qa++)
    #pragma unroll
    for (int hh=0; hh<2; hh++){
      float s = dacc[qa][hh];
      s += __shfl_xor(s, 16);
      s += __shfl_xor(s, 32);
      if (gq == 0) atomicAdd(&DN[hh][qa*16 + n], s);
    }
  #pragma unroll
  for (int qa=0; qa<2; qa++)
    #pragma unroll
    for (int hh=0; hh<2; hh++)
      #pragma unroll
      for (int db=0; db<2; db++)
        #pragma unroll
        for (int r=0; r<4; r++)
          atomicAdd(&R[(qa*16 + gq*4 + r)*64 + hh*32 + db*16 + n], o[qa][hh][db][r]);
  __syncthreads();
  if (lout && t < 64)
    lout[(size_t)(bz*2 + (t>>5))*LQ + qt*32 + (t&31)] = DN[t>>5][t&31];
  for (int e=t; e<2048; e+=256){
    int q = e >> 6, d = e & 63;
    ST[q*68 + d] = R[e] / DN[d>>5][q];
  }
  __syncthreads();                   // OACC dead; reuse R as WOT
  for (int e2=t; e2<4096; e2+=256){ int k=e2>>6, mo=e2&63; R[e2] = wo[mo*64+k]; }
  if (t < 64)       CB[t] = bo[t];
  else if (t < 128) CB[t] = g[t-64];
  else if (t < 192) CB[t] = be[t-128];
  __syncthreads();
  for (int r=0; r<8; r++){
    int tl = wv*8 + r;
    size_t gtok = (size_t)(bz*LQ + qt*32 + tl);
    float acc = CB[lane];
    for (int k=0; k<64; k++) acc += ST[tl*68 + k] * R[k*64 + lane];
    float rr = acc + bfu2f(h[gtok*64 + lane]);
    float s = rr;
    #pragma unroll
    for (int ofs=32; ofs; ofs>>=1) s += __shfl_xor(s, ofs);
    float mean = s * (1.f/64.f);
    float dv = rr - mean;
    float vs = dv*dv;
    #pragma unroll
    for (int ofs=32; ofs; ofs>>=1) vs += __shfl_xor(vs, ofs);
    float rstd = 1.f/sqrtf(vs*(1.f/64.f) + 1e-5f);
    h[gtok*64 + lane] = f2bu(dv*rstd*CB[64+lane] + CB[128+lane]);
  }
}

// ---------------- fused FFN + residual + LN (MFMA) ----------------
__global__ __launch_bounds__(256) void k_ffn(u16* __restrict__ h,
    const float* __restrict__ w1, const float* __restrict__ b1,
    const float* __restrict__ w2, const float* __restrict__ b2,
    const float* __restrict__ g, const float* __restrict__ be){
  __shared__ u16 W1L[128*64];      // [h1row][64 d] swizzled
  __shared__ u16 W2L[64*192];      // [o][6 kblk * 32] swizzled (4 W2 + 2 I)
  __shared__ u16 YL[64*64];        // y bf16 staging (swizzled by row)
  __shared__ float B1[128], B2F[64], G[64], Bb[64];
  const int t = threadIdx.x;
  for (int e=t; e<8192; e+=256){
    int row = e>>6, col = e&63;
    W1L[row*64 + (col ^ ((row&7)<<3))] = f2bu(w1[e]);
  }
  for (int e=t; e<12288; e+=256){
    int o = e/192, rem = e%192, u = rem>>5, gs = rem&31, gq2 = gs>>3, s = gs&7;
    float val;
    if (u < 4) val = w2[o*128 + u*32 + ((s>>2)<<4) + gq2*4 + (s&3)];
    else { int d = ((u-4)<<5) + gq2*8 + s; val = (d==o) ? 1.f : 0.f; }
    W2L[o*192 + ((u*32+gs) ^ ((o&7)<<3))] = f2bu(val);
  }
  if (t < 128) B1[t] = b1[t];
  if (t < 64){ B2F[t] = b2[t]; G[t] = g[t]; Bb[t] = be[t]; }
  __syncthreads();
  const int lane = t & 63, wv = t >> 6;
  const int n = lane & 15, gq = lane >> 4;
  const int tok0 = blockIdx.x*64 + wv*16;
  bf16x8 xf[2];
  xf[0] = *(const bf16x8*)(h + (size_t)(tok0+n)*64 + gq*8);
  xf[1] = *(const bf16x8*)(h + (size_t)(tok0+n)*64 + 32 + gq*8);
  f32x4 acc1[8];
  #pragma unroll
  for (int ct=0; ct<8; ct++){
    f32x4 c;
    #pragma unroll
    for (int r=0;r<4;r++) c[r] = B1[ct*16 + gq*4 + r];
    bf16x8 w1f0 = *(const bf16x8*)(W1L + (ct*16+n)*64 + ((gq*8) ^ ((n&7)<<3)));
    bf16x8 w1f1 = *(const bf16x8*)(W1L + (ct*16+n)*64 + ((32+gq*8) ^ ((n&7)<<3)));
    c = __builtin_amdgcn_mfma_f32_16x16x32_bf16(w1f0, xf[0], c, 0, 0, 0);
    c = __builtin_amdgcn_mfma_f32_16x16x32_bf16(w1f1, xf[1], c, 0, 0, 0);
    acc1[ct] = c;
  }
  f32x4 acc2[4];
  #pragma unroll
  for (int ot=0; ot<4; ot++)
    #pragma unroll
    for (int r=0;r<4;r++) acc2[ot][r] = B2F[ot*16 + gq*4 + r];
  #pragma unroll
  for (int u=0; u<6; u++){
    union { unsigned uu[4]; bf16x8 v; } bfr;
    if (u < 4){
      #pragma unroll
      for (int i=0;i<4;i++){
        int ct = u*2 + (i>>1);
        float a = fmaxf(acc1[ct][(2*i)&3], 0.f);
        float b = fmaxf(acc1[ct][(2*i+1)&3], 0.f);
        bfr.uu[i] = (unsigned)f2bu(a) | ((unsigned)f2bu(b) << 16);
      }
    } else {
      bfr.v = xf[u-4];
    }
    #pragma unroll
    for (int ot=0; ot<4; ot++){
      bf16x8 w2f = *(const bf16x8*)(W2L + (ot*16+n)*192 + ((u*32+gq*8) ^ ((n&7)<<3)));
      acc2[ot] = __builtin_amdgcn_mfma_f32_16x16x32_bf16(w2f, bfr.v, acc2[ot], 0, 0, 0);
    }
  }
  float s1 = 0.f;
  #pragma unroll
  for (int ot=0;ot<4;ot++)
    #pragma unroll
    for (int r=0;r<4;r++) s1 += acc2[ot][r];
  s1 += __shfl_xor(s1, 16); s1 += __shfl_xor(s1, 32);
  float mean = s1 * (1.f/64.f);
  float s2 = 0.f;
  #pragma unroll
  for (int ot=0;ot<4;ot++)
    #pragma unroll
    for (int r=0;r<4;r++){ float dv = acc2[ot][r]-mean; s2 += dv*dv; }
  s2 += __shfl_xor(s2, 16); s2 += __shfl_xor(s2, 32);
  float rstd = 1.f/sqrtf(s2*(1.f/64.f) + 1e-5f);
  #pragma unroll
  for (int ot=0;ot<4;ot++)
    #pragma unroll
    for (int r=0;r<4;r++){
      int o = ot*16 + gq*4 + r;
      float yv = (acc2[ot][r]-mean)*rstd*G[o] + Bb[o];
      YL[(wv*16+n)*64 + (o ^ ((n&7)<<3))] = f2bu(yv);
    }
  __syncthreads();
  unsigned* h32 = (unsigned*)(h + (size_t)(blockIdx.x)*64*64);
  #pragma unroll
  for (int i=0;i<8;i++){
    int idx = i*64 + lane;
    int row = wv*16 + (idx>>5), c32 = idx&31;
    unsigned vv = *(const unsigned*)(YL + row*64 + ((c32*2) ^ ((row&7)<<3)));
    h32[row*32 + c32] = vv;
  }
}

// ---------------- pass2 (MFMA): scores -> attn_w FLOAT32 (+partial imp) -----
// DOIMP=1: grid 4096, nper=512. nid<3840: pass2 for bz=nid>>8, rem=nid&255,
// qt=rem>>3, ks=rem&7, kt in [ks*4,ks*4+4). nid>=3840: fused bz-15 importance
// (idx=nid-3840: qt=idx>>3, ks=idx&7) -> atomics into imp15.
// DOIMP=0: grid 256, nper=32, bz0=15 (attn_w for batch 15).
// Importance partials: LDS PIMP, one non-atomic store to part[qt][bz][2048].
template<int DOIMP>
__global__ __launch_bounds__(256) void k_pass2(const u16* __restrict__ qk_r15,
    const u16* __restrict__ qk_ws, const float* __restrict__ l2,
    float* __restrict__ part, float* __restrict__ wout,
    float* __restrict__ imp15, int bz0, int nper){
  __shared__ float STG[64*68];       // [q][j] staging, per-wave-private rows
  __shared__ float INVL[128];
  __shared__ float PIMP[256];
  const int x = blockIdx.x;
  const int nid = (x & 7)*nper + (x >> 3);
  const int t = threadIdx.x;
  const int lane = t & 63, wv = t >> 6;
  const int n = lane & 15, gq = lane >> 4;
  const f32x4 FZ = {0.f, 0.f, 0.f, 0.f};

  if (DOIMP && nid >= 3840){
    // ---- fused bz-15 importance ----
    const int idx = nid - 3840;
    const int qt = idx >> 3, ks = idx & 7;
    if (t < 128) INVL[t] = 1.f / l2[(size_t)(15*2 + (t>>6))*LQ + qt*64 + (t&63)];
    PIMP[t] = 0.f;
    bf16x8 qf0, qf1;
    {
      const u16* qrow = qk_rowp(qk_r15, qk_ws, 15, qt*64 + wv*16 + n);
      qf0 = *(const bf16x8*)(qrow + gq*8);
      qf1 = *(const bf16x8*)(qrow + 32 + gq*8);
    }
    __syncthreads();
    float iv0[4], iv1[4];
    #pragma unroll
    for (int r=0;r<4;r++){
      iv0[r] = INVL[wv*16 + gq*4 + r];
      iv1[r] = INVL[64 + wv*16 + gq*4 + r];
    }
    for (int kt=ks*4; kt<ks*4+4; kt++){
      #pragma unroll
      for (int jb=0; jb<4; jb++){
        const u16* kr = qk_rowp(qk_r15, qk_ws, 15, kt*64 + jb*16 + n);
        bf16x8 kf0 = *(const bf16x8*)(kr + 64 + gq*8);
        bf16x8 kf1 = *(const bf16x8*)(kr + 96 + gq*8);
        f32x4 e0 = __builtin_amdgcn_mfma_f32_16x16x32_bf16(qf0, kf0, FZ, 0, 0, 0);
        f32x4 e1 = __builtin_amdgcn_mfma_f32_16x16x32_bf16(qf1, kf1, FZ, 0, 0, 0);
        float cs = 0.f;
        #pragma unroll
        for (int r=0;r<4;r++)
          cs += 0.5f*(__expf(e0[r])*iv0[r] + __expf(e1[r])*iv1[r]);
        cs += __shfl_xor(cs, 16);
        cs += __shfl_xor(cs, 32);
        if (gq == 0) atomicAdd(&PIMP[(kt-ks*4)*64 + jb*16 + n], cs);
      }
    }
    __syncthreads();
    atomicAdd(&imp15[ks*256 + t], PIMP[t]);
    return;
  }

  // ---- pass2 body ----
  const int bz = bz0 + (nid >> 8);
  const int rem = nid & 255;
  const int qt = rem >> 3, ks = rem & 7;
  if (t < 128) INVL[t] = 1.f / l2[(size_t)(bz*2 + (t>>6))*LQ + qt*64 + (t&63)];
  if (DOIMP) PIMP[t] = 0.f;
  bf16x8 qf0, qf1;
  {
    const u16* qrow = qk_rowp(qk_r15, qk_ws, bz, qt*64 + wv*16 + n);
    qf0 = *(const bf16x8*)(qrow + gq*8);
    qf1 = *(const bf16x8*)(qrow + 32 + gq*8);
  }
  __syncthreads();
  const float iv0 = INVL[wv*16 + n], iv1 = INVL[64 + wv*16 + n];
  for (int kt = ks*4; kt < ks*4 + 4; kt++){
    #pragma unroll
    for (int jb=0; jb<4; jb++){
      const u16* kr = qk_rowp(qk_r15, qk_ws, bz, kt*64 + jb*16 + n);
      bf16x8 kf0 = *(const bf16x8*)(kr + 64 + gq*8);
      bf16x8 kf1 = *(const bf16x8*)(kr + 96 + gq*8);
      f32x4 e0 = __builtin_amdgcn_mfma_f32_16x16x32_bf16(kf0, qf0, FZ, 0, 0, 0);
      f32x4 e1 = __builtin_amdgcn_mfma_f32_16x16x32_bf16(kf1, qf1, FZ, 0, 0, 0);
      float4 w4;
      w4.x = 0.5f*(__expf(e0[0])*iv0 + __expf(e1[0])*iv1);
      w4.y = 0.5f*(__expf(e0[1])*iv0 + __expf(e1[1])*iv1);
      w4.z = 0.5f*(__expf(e0[2])*iv0 + __expf(e1[2])*iv1);
      w4.w = 0.5f*(__expf(e0[3])*iv0 + __expf(e1[3])*iv1);
      *(float4*)(&STG[(wv*16 + n)*68 + jb*16 + 4*gq]) = w4;
    }
    size_t base = 1 + (size_t)bz*LQ*LQ + (size_t)(qt*64)*LQ + (size_t)kt*64;
    float p = 0.f;
    for (int r=0; r<16; r++){
      int q = wv*16 + r;
      float v = STG[q*68 + lane];
      __builtin_nontemporal_store(v, &wout[base + (size_t)q*LQ + lane]);
      p += v;
    }
    if (DOIMP) atomicAdd(&PIMP[(kt-ks*4)*64 + lane], p);
  }
  if (DOIMP){
    __syncthreads();
    part[((size_t)qt*16 + bz)*LQ + ks*256 + t] = PIMP[t];
  }
}

// ---------------- reduce + top-k + memory reader + loss (per batch) ---------
// 256 threads: blocks 0-14 reduce their batch's 32 qt-partials from Ppart
// (coalesced); block 15 reads imp15. Top-k + loss run wave-local in wave 0
// (shuffle argmax; no cross-wave barriers after the single __syncthreads).
__global__ __launch_bounds__(256) void k_select(const float* __restrict__ part,
    const float* __restrict__ imp15, const u16* __restrict__ h,
    const int* __restrict__ query, const int* __restrict__ target,
    const float* __restrict__ qemb, const float* __restrict__ rq_w, const float* __restrict__ rq_b,
    const float* __restrict__ ro_w, const float* __restrict__ ro_b, float* __restrict__ out0){
  __shared__ float v[2048];
  const int b = blockIdx.x, t = threadIdx.x;
  if (b < 15){
    for (int c=t; c<2048; c+=256){
      float s = 0.f;
      #pragma unroll 8
      for (int qt=0; qt<32; qt++) s += part[((size_t)qt*16 + b)*LQ + c];
      v[c] = s;
    }
  } else {
    for (int c=t; c<2048; c+=256) v[c] = imp15[c];
  }
  __syncthreads();
  if (t >= 64) return;
  const int lane = t;
  int topi[8];
  for (int m=0; m<8; m++){
    float best = -1e30f; int besti = 1<<30;
    for (int i=lane; i<2048; i+=64)
      if (v[i] > best || (v[i] == best && i < besti)){ best = v[i]; besti = i; }
    #pragma unroll
    for (int off=32; off; off>>=1){
      float ob = __shfl_xor(best, off);
      int   oi = __shfl_xor(besti, off);
      if (ob > best || (ob == best && oi < besti)){ best = ob; besti = oi; }
    }
    int c = (besti < 0) ? 0 : (besti > 2047 ? 2047 : besti);
    topi[m] = c;
    v[c] = -1e30f;   // all 64 lanes write the same value (same-wave ordering)
  }
  float mv[8];
  #pragma unroll
  for (int m=0; m<8; m++){
    int idx = topi[m] & 2047;
    mv[m] = bfu2f(h[(size_t)(b*LQ + idx)*64 + lane]);
  }
  float qh = qemb[((query[b]&63)<<6) + lane];
  float qd = rq_b[lane];
  for (int k=0;k<64;k++) qd += __shfl(qh,k) * rq_w[lane*64 + k];
  float sc[8];
  #pragma unroll
  for (int m=0;m<8;m++){
    float p = qd * mv[m];
    #pragma unroll
    for (int o=32;o;o>>=1) p += __shfl_xor(p,o);
    sc[m] = p * 0.125f;   // 1/sqrt(64)
  }
  float mx = sc[0];
  #pragma unroll
  for (int m=1;m<8;m++) mx = fmaxf(mx, sc[m]);
  float den = 0.f, rd = 0.f;
  #pragma unroll
  for (int m=0;m<8;m++){ float w = __expf(sc[m]-mx); den += w; rd += w*mv[m]; }
  rd /= den;
  float lg = ro_b[lane];
  for (int d=0;d<64;d++) lg += __shfl(rd,d) * ro_w[lane*64 + d];
  float lmx = lg;
  #pragma unroll
  for (int o=32;o;o>>=1) lmx = fmaxf(lmx, __shfl_xor(lmx,o));
  float ex = __expf(lg - lmx), es = ex;
  #pragma unroll
  for (int o=32;o;o>>=1) es += __shfl_xor(es,o);
  float lt = __shfl(lg, target[b]&63);
  if (lane == 0) atomicAdd(out0, -(lt - lmx - logf(es)) * (1.f/16.f));
}

// ---------------- launch ----------------
extern "C" void kernel_launch(void* const* d_in, const int* in_sizes, int n_in,
                              void* d_out, int out_size, void* d_ws, size_t ws_size,
                              hipStream_t stream){
  const int*   seq    = (const int*)  d_in[0];
  const int*   query  = (const int*)  d_in[1];
  const int*   target = (const int*)  d_in[2];
  const float* embed  = (const float*)d_in[3];
  const float* a1_wi  = (const float*)d_in[4];
  const float* a1_bi  = (const float*)d_in[5];
  const float* a1_wo  = (const float*)d_in[6];
  const float* a1_bo  = (const float*)d_in[7];
  const float* ff1_w1 = (const float*)d_in[8];
  const float* ff1_b1 = (const float*)d_in[9];
  const float* ff1_w2 = (const float*)d_in[10];
  const float* ff1_b2 = (const float*)d_in[11];
  const float* ln1a_g = (const float*)d_in[12];
  const float* ln1a_b = (const float*)d_in[13];
  const float* ln1b_g = (const float*)d_in[14];
  const float* ln1b_b = (const float*)d_in[15];
  const float* a2_wi  = (const float*)d_in[16];
  const float* a2_bi  = (const float*)d_in[17];
  const float* a2_wo  = (const float*)d_in[18];
  const float* a2_bo  = (const float*)d_in[19];
  const float* ff2_w1 = (const float*)d_in[20];
  const float* ff2_b1 = (const float*)d_in[21];
  const float* ff2_w2 = (const float*)d_in[22];
  const float* ff2_b2 = (const float*)d_in[23];
  const float* ln2a_g = (const float*)d_in[24];
  const float* ln2a_b = (const float*)d_in[25];
  const float* ln2b_g = (const float*)d_in[26];
  const float* ln2b_b = (const float*)d_in[27];
  const float* rq_w   = (const float*)d_in[28];
  const float* rq_b   = (const float*)d_in[29];
  const float* ro_w   = (const float*)d_in[30];
  const float* ro_b   = (const float*)d_in[31];
  const float* qemb   = (const float*)d_in[32];

  // d_ws
  char* wsb      = (char*)d_ws;
  u16*  qk_ws    = (u16*)(wsb);                // 524,288 B (batch 15 [Qs|K])
  float* ws_imp  = (float*)(wsb + 524288);     // 131,072 B (row 15 only)
  float* ws_l    = (float*)(wsb + 655360);     // 262,144 B
  float* imp15   = ws_imp + 15*LQ;

  // d_out (FLOAT32, 268,435,460 B) + scratch parking
  float* out_f  = (float*)d_out;
  u16* qk1     = (u16*)((char*)d_out + 4194368);     // 8 MB layer-1 [Qs|K]
  u16* vg1     = (u16*)((char*)d_out + 12582976);    // 4 MB layer-1 V (j-tiled)
  u16* vg2     = (u16*)((char*)d_out + 4194368);     // 4 MB layer-2 V (j-tiled)
  u16* qk_r15  = (u16*)((char*)d_out + 251658304);   // 7.5 MB, region-15 head
  u16* h16     = (u16*)((char*)d_out + 259522624);   // 4 MB, region-15 tail
  float* Ppart = (float*)((char*)d_out + 263716928); // 4 MB, region-15 tail

  // layer 1 (embed fused into qkv; block 0 zeroes imp15 + out_f[0])
  k_qkv<0><<<512,256,0,stream>>>(nullptr, seq, embed, a1_wi, a1_bi,
                                 qk1, nullptr, nullptr, vg1, h16, imp15, out_f);
  k_attn_ln<0><<<1024,256,0,stream>>>(qk1, nullptr, vg1,
                                      a1_wo, a1_bo, ln1a_g, ln1a_b, h16, nullptr);
  k_ffn<<<512,256,0,stream>>>(h16, ff1_w1, ff1_b1, ff1_w2, ff1_b2, ln1b_g, ln1b_b);
  // layer 2
  k_qkv<1><<<512,256,0,stream>>>(h16, nullptr, nullptr, a2_wi, a2_bi,
                                 nullptr, qk_r15, qk_ws, vg2, nullptr, nullptr, nullptr);
  k_attn_ln<1><<<1024,256,0,stream>>>(qk_r15, qk_ws, vg2,
                                      a2_wo, a2_bo, ln2a_g, ln2a_b, h16, ws_l);
  k_ffn<<<512,256,0,stream>>>(h16, ff2_w1, ff2_b1, ff2_w2, ff2_b2, ln2b_g, ln2b_b);
  // attn_w bz0-14 + partial importance + fused bz15 importance (grid 4096;
  // destroys regions 0-14; h16/Ppart safe in region-15 tail)
  k_pass2<1><<<4096,256,0,stream>>>(qk_r15, qk_ws, ws_l, Ppart, out_f, imp15, 0, 512);
  // reduce + topk + loss (h16/Ppart still alive); loss -> out_f[0]
  k_select<<<16,256,0,stream>>>(Ppart, imp15, h16, query, target, qemb,
                                rq_w, rq_b, ro_w, ro_b, out_f);
  // attn_w bz15 (overwrites region 15: qk_r15 + h16 + Ppart now dead)
  k_pass2<0><<<256,256,0,stream>>>(qk_r15, qk_ws, ws_l, nullptr, out_f, nullptr, 15, 32);
}